// Round 13
// baseline (110.890 us; speedup 1.0000x reference)
//
#include <hip/hip_runtime.h>
#include <hip/hip_bf16.h>

#pragma clang fp contract(off)

#define NN   230400   // H*W*A
#define NK   128      // gt boxes
#define HW_  25600    // H*W
#define NA   9
#define NBLK 900      // NN/256
#define BINS 8192
#define BCAP 64

// ---- scalar slots in ws (S_WL on its own cacheline) ----
enum { S_FG_ACTIVE=0, S_FG_TH, S_NFG_FINAL, S_BG_ACTIVE, S_BG_TH, S_NUM_EX };
#define S_WL 64

__device__ __forceinline__ unsigned encf(float f) {
    unsigned u = __float_as_uint(f);
    return (u & 0x80000000u) ? ~u : (u | 0x80000000u);
}
__device__ __forceinline__ float decf(unsigned e) {
    unsigned u = (e & 0x80000000u) ? (e & 0x7FFFFFFFu) : ~e;
    return __uint_as_float(u);
}
// The ONE IoU expression (identical rounding at every use site; contract off).
__device__ __forceinline__ void iou_parts(float4 a, float ba, float4 g, float ga,
                                          float& I, float& D) {
    float iw = fmaxf(fminf(a.z, g.z) - fmaxf(a.x, g.x) + 1.0f, 0.0f);
    float ih = fmaxf(fminf(a.w, g.w) - fmaxf(a.y, g.y) + 1.0f, 0.0f);
    I = iw * ih;
    D = ba + ga - I;          // (ba+ga)-I, same assoc everywhere
}
__device__ __forceinline__ unsigned vbin(float nz) {
    unsigned b = (unsigned)(nz * 8192.0f);
    return b > 8191u ? 8191u : b;
}

// Prep: default outputs for ALL anchors + compact inside-anchor index list.
__global__ __launch_bounds__(256) void k_prep(
    const float4* __restrict__ anchors, const float* __restrict__ iminfo,
    float* __restrict__ maxov, unsigned char* __restrict__ argm,
    unsigned* __restrict__ wl, unsigned* __restrict__ sc) {
    int t = threadIdx.x;
    int i = blockIdx.x * 256 + t;
    float4 a = anchors[i];
    float imh = iminfo[0], imw = iminfo[1];
    bool ins = (a.x >= 0.0f) && (a.y >= 0.0f) && (a.z < imw) && (a.w < imh);
    maxov[i] = -1.0f;                  // k_rowcol overwrites inside rows
    argm[i]  = 0;
    unsigned long long m = __ballot(ins);
    if (m) {
        int lane = t & 63;
        int leader = __ffsll((unsigned long long)m) - 1;
        unsigned base = 0;
        if (lane == leader) base = atomicAdd(&sc[S_WL], (unsigned)__popcll(m));
        base = __shfl(base, leader, 64);
        if (ins) {
            unsigned off = (unsigned)__popcll(m & ((1ull << lane) - 1ull));
            wl[base + off] = (unsigned)i;
        }
    }
}

// Row+col in ONE visit per pair, inside anchors only (compacted list).
// Block: 128 anchors x 2 k-halves. Per-column LDS running max (value bits),
// seeded from global gtm; combined gate -> rare exact divide. End: R6-style
// racy-prefiltered global atomicMax flush (<=128 per block).
__global__ __launch_bounds__(256) void k_rowcol(
    const float4* __restrict__ anchors, const float4* __restrict__ gt,
    const unsigned* __restrict__ wl, const unsigned* __restrict__ sc,
    float* __restrict__ maxov, unsigned char* __restrict__ argm,
    unsigned* __restrict__ gtm) {
    __shared__ float4 sg[NK];
    __shared__ float  sga[NK];
    __shared__ unsigned colb[NK];      // per-column running max (value bits)
    __shared__ float  abV[2][128];
    __shared__ unsigned char aidx[2][128];
    int t = threadIdx.x;
    if (t < NK) {
        float4 g = gt[t];
        sg[t] = g;
        sga[t] = (g.z - g.x + 1.0f) * (g.w - g.y + 1.0f);
        unsigned e0 = gtm[t];          // racy monotone lower bound
        colb[t] = (e0 == 0u) ? 0u : __float_as_uint(decf(e0));
    }
    __syncthreads();
    unsigned cnt = sc[S_WL];
    int lo = t & 127, h = t >> 7;      // h uniform per wave
    for (unsigned base = blockIdx.x * 128u; base < cnt; base += gridDim.x * 128u) {
        unsigned j = base + (unsigned)lo;
        bool valid = j < cnt;
        unsigned ai = valid ? wl[j] : 0u;
        float4 a = anchors[ai];                    // gather (L2/L3-hot)
        float ba = (a.z - a.x + 1.0f) * (a.w - a.y + 1.0f);
        float vb = 0.0f;                           // all-zero row -> max 0
        int idx = h * 64;                          // first k of this half
        for (int kk = 0; kk < 64; ++kk) {
            int k = h * 64 + kk;
            float I, D; iou_parts(a, ba, sg[k], sga[k], I, D);
            float cbf = __uint_as_float(colb[k]);  // racy, monotone
            float m = fminf(vb, cbf);
            float mD = m * D;
            // fires whenever round(I/D) could beat row OR col record
            // (1-ulp-margined; misses impossible by monotone rounding)
            if (valid & (I > 0.0f) & (I > mD - 1e-6f * mD)) {
                float v = I / D;                   // exact IEEE, THE value
                if (v > vb) { vb = v; idx = k; }   // strict > = first max
                if (v > cbf) atomicMax(&colb[k], __float_as_uint(v));
            }
        }
        abV[h][lo]  = vb;
        aidx[h][lo] = (unsigned char)idx;
        __syncthreads();
        if (t < 128 && (base + (unsigned)t) < cnt) {
            float v0 = abV[0][t], v1 = abV[1][t];
            bool c = v1 > v0;                      // strict: half 0 wins ties
            unsigned ai2 = wl[base + t];
            maxov[ai2] = c ? v1 : v0;
            argm[ai2]  = c ? aidx[1][t] : aidx[0][t];
        }
        __syncthreads();                           // abV reuse next tile
    }
    __syncthreads();                               // all colb updates done
    if (t < NK) {
        unsigned e = encf(__uint_as_float(colb[t]));
        if (e > gtm[t]) atomicMax(&gtm[t], e);     // racy prefilter; atomic wins
    }
}

// Labels + bbox targets: in-block gt sort (defer prune), thresholds from maxov,
// inline gt-best for deferred anchors, value-binned hist+bucket, out1 targets.
__global__ __launch_bounds__(256) void k_labels(
    const float4* __restrict__ anchors, const float4* __restrict__ gt,
    const unsigned* __restrict__ gtm,
    const float* __restrict__ maxov, const unsigned char* __restrict__ argm,
    const float* __restrict__ noise,
    float* __restrict__ labels,
    unsigned* __restrict__ hfv, unsigned* __restrict__ hbv,
    float* __restrict__ bfv, float* __restrict__ bbv,
    float4* __restrict__ out1) {
    __shared__ float4 sg[NK];            // sorted gt (defer loop)
    __shared__ float  sga[NK];
    __shared__ float  sgm[NK];
    __shared__ float4 sgo[NK];           // original-order gt (targets)
    __shared__ unsigned se[NK];
    int t = threadIdx.x;
    if (t < NK) se[t] = gtm[t];
    __syncthreads();
    if (t < NK) {
        unsigned e = se[t];
        int rank = 0;
        for (int j = 0; j < NK; ++j) {
            unsigned ej = se[j];
            rank += (ej < e) || (ej == e && j < t);
        }
        float4 g = gt[t];
        sgo[t]    = g;
        sg[rank]  = g;
        sga[rank] = (g.z - g.x + 1.0f) * (g.w - g.y + 1.0f);
        sgm[rank] = (e == 0u) ? 0.0f : decf(e);    // never-updated col: max is 0
    }
    __syncthreads();
    int i = blockIdx.x * 256 + t;
    float mo = maxov[i];
    bool ins = mo >= 0.0f;
    float smin = sgm[0];
    float lab = -1.0f;
    if (ins && mo < 0.3f)  lab = 0.0f;
    if (ins && mo >= 0.7f) lab = 1.0f;
    float4 a = anchors[i];
    bool defer = ins && (mo >= smin) && (mo < 0.7f);
    if (defer) {                               // rare -> divergence cost small
        float ba = (a.z - a.x + 1.0f) * (a.w - a.y + 1.0f);
        bool gb = false;
        for (int q = 0; q < NK; ++q) {
            float gm = sgm[q];
            if (gm > mo) break;                // sorted: no later column can match
            float I, D; iou_parts(a, ba, sg[q], sga[q], I, D);
            float v = I / D;                   // bit-identical to k_rowcol rounding
            gb = gb || (v == gm);
        }
        if (gb) lab = 1.0f;
    }
    labels[i] = lab;
    float nz = noise[i];
    if (lab == 1.0f) {
        unsigned b = vbin(nz);
        unsigned s = atomicAdd(&hfv[b], 1u);
        if (s < BCAP) bfv[b * BCAP + s] = nz;
    } else if (lab == 0.0f) {
        unsigned b = vbin(nz);
        unsigned s = atomicAdd(&hbv[b], 1u);
        if (s < BCAP) bbv[b * BCAP + s] = nz;
    }
    // ---- bbox regression targets (selection-independent) ----
    {
        float4 g = sgo[argm[i]];
        float ew = a.z - a.x + 1.0f, eh = a.w - a.y + 1.0f;
        float ecx = a.x + 0.5f * ew,  ecy = a.y + 0.5f * eh;
        float gw = g.z - g.x + 1.0f,  gh = g.w - g.y + 1.0f;
        float gcx = g.x + 0.5f * gw,  gcy = g.y + 0.5f * gh;
        float t0 = (gcx - ecx) / ew;
        float t1 = (gcy - ecy) / eh;
        float t2 = logf(gw / ew);
        float t3 = logf(gh / eh);
        if (!ins) { t0 = 0.0f; t1 = 0.0f; t2 = 0.0f; t3 = 0.0f; }   // outside
        out1[i] = make_float4(t0, t1, t2, t3);
    }
}

// Selection body: linear 8192-bin scan -> bin+rem -> exact rank among <=64 values.
__device__ __forceinline__ void sel_body(
    const unsigned* __restrict__ hist, const float* __restrict__ bucket,
    unsigned* __restrict__ sc, int isBg,
    int* csum, int* suf, int* sscal, float* sv) {
    int t = threadIdx.x;
    const unsigned* hp = hist + t * 32;
    int s = 0;
    for (int b = 0; b < 32; ++b) s += (int)hp[b];
    csum[t] = s;
    if (t == 0) { sscal[0] = 0; sscal[1] = 1; }
    __syncthreads();
    if (t == 0) {
        int run = 0;
        for (int c = 255; c >= 0; --c) { suf[c] = run; run += csum[c]; }
        sscal[2] = run;
    }
    __syncthreads();
    int total = sscal[2];
    int k, active;
    if (isBg) {
        int nfg = (int)sc[S_NFG_FINAL];
        int nb = 256 - nfg;
        active = total > nb;
        k = nb < 1 ? 1 : nb;
    } else {
        active = total > 128;
        k = 128;
    }
    if (!active) {
        if (t == 0) {
            if (isBg) { sc[S_BG_ACTIVE] = 0u; sc[S_NUM_EX] = sc[S_NFG_FINAL] + (unsigned)total; }
            else      { sc[S_FG_ACTIVE] = 0u; sc[S_NFG_FINAL] = (unsigned)total; }
        }
    } else {
        int above = suf[t];
        if (above < k && k <= above + csum[t]) {
            int c = above;
            for (int b = 31; b >= 0; --b) {
                int hh = (int)hp[b];
                c += hh;
                if (c >= k) { sscal[0] = t * 32 + b; sscal[1] = k - (c - hh); break; }
            }
        }
    }
    __syncthreads();
    if (active) {                                  // block-uniform condition
        int bstar = sscal[0], rem = sscal[1];
        int cnt = (int)hist[bstar];
        if (cnt > BCAP) cnt = BCAP;
        if (t < BCAP) sv[t] = (t < cnt) ? bucket[bstar * BCAP + t] : -INFINITY;
        __syncthreads();
        if (t < cnt) {
            float v = sv[t];
            int a = 0, b2 = 0;
            for (int q = 0; q < cnt; ++q) { float u = sv[q]; a += (u > v); b2 += (u == v); }
            if (a < rem && rem <= a + b2) {        // v is the k-th largest (tie-exact)
                unsigned nk = (unsigned)(k - rem + a + b2);   // count(score >= th)
                if (isBg) { sc[S_BG_TH] = __float_as_uint(v); sc[S_BG_ACTIVE] = 1u;
                            sc[S_NUM_EX] = sc[S_NFG_FINAL] + nk; }
                else      { sc[S_FG_TH] = __float_as_uint(v); sc[S_FG_ACTIVE] = 1u;
                            sc[S_NFG_FINAL] = nk; }
            }
        }
    }
    __syncthreads();                               // publish sc before next pass
}

__global__ __launch_bounds__(256) void k_select(
    const unsigned* __restrict__ hfv, const float* __restrict__ bfv,
    const unsigned* __restrict__ hbv, const float* __restrict__ bbv,
    unsigned* __restrict__ sc) {
    __shared__ int csum[256];
    __shared__ int suf[256];
    __shared__ int sscal[3];
    __shared__ float sv[BCAP];
    sel_body(hfv, bfv, sc, 0, csum, suf, sscal, sv);
    sel_body(hbv, bbv, sc, 1, csum, suf, sscal, sv);
}

// Final: pure streaming. Apply disables; scatter permuted label; weights.
__global__ __launch_bounds__(256) void k_final(
    const float* __restrict__ noise, const float* __restrict__ labels,
    const unsigned* __restrict__ sc,
    float* __restrict__ out0, float4* __restrict__ out2, float4* __restrict__ out3) {
    int i = blockIdx.x * 256 + threadIdx.x;
    unsigned fga = sc[S_FG_ACTIVE], bga = sc[S_BG_ACTIVE];
    float thf = __uint_as_float(sc[S_FG_TH]);
    float thb = __uint_as_float(sc[S_BG_TH]);

    float lab = labels[i];
    float nz = noise[i];
    if (fga && lab == 1.0f && nz < thf) lab = -1.0f;
    if (bga && lab == 0.0f && nz < thb) lab = -1.0f;

    // permuted label: src i = cell*NA + a0 -> dest a0*HW + cell (scatter write)
    int cell = i / NA, a0 = i - cell * NA;
    out0[a0 * HW_ + cell] = lab;

    float biw = (lab == 1.0f) ? 1.0f : 0.0f;
    out2[i] = make_float4(biw, biw, biw, biw);

    float inv = 1.0f / (float)sc[S_NUM_EX];
    float bow = (lab >= 0.0f) ? inv : 0.0f;
    out3[i] = make_float4(bow, bow, bow, bow);
}

extern "C" void kernel_launch(void* const* d_in, const int* in_sizes, int n_in,
                              void* d_out, int out_size, void* d_ws, size_t ws_size,
                              hipStream_t stream) {
    const float4* anchors = (const float4*)d_in[0];
    const float4* gt      = (const float4*)d_in[1];
    const float*  iminfo  = (const float*)d_in[2];
    const float*  noise   = (const float*)d_in[3];

    float*  out0 = (float*)d_out;                  // NN
    float4* out1 = (float4*)(out0 + NN);           // NN x 4 (written by k_labels)
    float4* out2 = (float4*)(out0 + NN + 4 * NN);  // NN x 4
    float4* out3 = (float4*)(out0 + NN + 8 * NN);  // NN x 4

    // value buckets borrow the out2/out3 regions (524288 floats each fits in
    // 921600): written by k_labels, read by k_select, then k_final overwrites.
    float* bfv = (float*)out2;
    float* bbv = (float*)out3;

    char* ws = (char*)d_ws;
    unsigned* sc   = (unsigned*)ws;                         // 128 u32 (S_WL @+256B)
    unsigned* gtm  = (unsigned*)(ws + 512);                 // 128 u32
    unsigned* hfv  = (unsigned*)(ws + 4096);                // 8192 u32
    unsigned* hbv  = hfv + BINS;                            // 8192 u32 -> ends 69632
    float* labels  = (float*)(ws + 69632);                  // NN f32
    float* maxov   = labels + NN;                           // NN f32
    unsigned char* argm = (unsigned char*)(maxov + NN);     // NN u8
    unsigned* wl   = (unsigned*)(ws + 2143232);             // NN u32 (inside list)

    hipMemsetAsync(ws, 0, 69632, stream);          // sc+gtm+hists (DMA node)
    k_prep<<<NBLK, 256, 0, stream>>>(anchors, iminfo, maxov, argm, wl, sc);
    k_rowcol<<<1024, 256, 0, stream>>>(anchors, gt, wl, sc, maxov, argm, gtm);
    k_labels<<<NBLK, 256, 0, stream>>>(anchors, gt, gtm, maxov, argm, noise,
                                       labels, hfv, hbv, bfv, bbv, out1);
    k_select<<<1, 256, 0, stream>>>(hfv, bfv, hbv, bbv, sc);
    k_final<<<NBLK, 256, 0, stream>>>(noise, labels, sc, out0, out2, out3);
}

// Round 14
// 70.352 us; speedup vs baseline: 1.5762x; 1.5762x over previous
//
#include <hip/hip_runtime.h>
#include <hip/hip_bf16.h>

#pragma clang fp contract(off)

#define NN   230400   // H*W*A
#define NK   128      // gt boxes
#define HW_  25600    // H*W
#define NA   9
#define NBLK 900      // NN/256
#define BINS 8192
#define BCAP 64

// ---- scalar slots in ws ----
enum { S_FG_ACTIVE=0, S_FG_TH, S_NFG_FINAL, S_BG_ACTIVE, S_BG_TH, S_NUM_EX };

__device__ __forceinline__ unsigned encf(float f) {
    unsigned u = __float_as_uint(f);
    return (u & 0x80000000u) ? ~u : (u | 0x80000000u);
}
__device__ __forceinline__ float decf(unsigned e) {
    unsigned u = (e & 0x80000000u) ? (e & 0x7FFFFFFFu) : ~e;
    return __uint_as_float(u);
}
// The ONE IoU expression (identical rounding at every use site; contract off).
__device__ __forceinline__ void iou_parts(float4 a, float ba, float4 g, float ga,
                                          float& I, float& D) {
    float iw = fmaxf(fminf(a.z, g.z) - fmaxf(a.x, g.x) + 1.0f, 0.0f);
    float ih = fmaxf(fminf(a.w, g.w) - fmaxf(a.y, g.y) + 1.0f, 0.0f);
    I = iw * ih;
    D = ba + ga - I;          // (ba+ga)-I, same assoc everywhere
}
__device__ __forceinline__ unsigned vbin(float nz) {
    unsigned b = (unsigned)(nz * 8192.0f);
    return b > 8191u ? 8191u : b;
}

// Row+col in ONE visit per pair (R12-validated gate), ALL anchors (no compaction
// -- dead lanes are cheaper than any global-atomic compaction on this chip).
// Block: 128 anchors x 2 k-halves. Per-column LDS running max seeded from gtm;
// combined gate -> rare exact divide. End: R6-proven racy-prefiltered flush.
__global__ __launch_bounds__(256) void k_rowcol(
    const float4* __restrict__ anchors, const float4* __restrict__ gt,
    const float* __restrict__ iminfo, float* __restrict__ maxov,
    unsigned char* __restrict__ argm, unsigned* __restrict__ gtm) {
    __shared__ float4 sg[NK];
    __shared__ float  sga[NK];
    __shared__ float4 sa[128];
    __shared__ float  sba[128];        // real ba, or -1 if outside
    __shared__ unsigned colb[NK];      // per-column running max (value bits)
    __shared__ float  abV[2][128];
    __shared__ unsigned char aidx[2][128];
    int t = threadIdx.x;
    if (t < NK) {
        float4 g = gt[t];
        sg[t] = g;
        sga[t] = (g.z - g.x + 1.0f) * (g.w - g.y + 1.0f);
        unsigned e0 = gtm[t];          // racy monotone lower bound
        colb[t] = (e0 == 0u) ? 0u : __float_as_uint(decf(e0));
    }
    int base = blockIdx.x * 128;
    if (t < 128) {
        float4 a = anchors[base + t];
        sa[t] = a;
        float imh = iminfo[0], imw = iminfo[1];
        bool ins = (a.x >= 0.0f) && (a.y >= 0.0f) && (a.z < imw) && (a.w < imh);
        float ba = (a.z - a.x + 1.0f) * (a.w - a.y + 1.0f);
        sba[t] = ins ? ba : -1.0f;
    }
    __syncthreads();
    int lo = t & 127, h = t >> 7;      // h uniform per wave
    {
        float4 a = sa[lo];
        float ba = sba[lo];
        bool ins = ba >= 0.0f;
        float vb = 0.0f;               // inside all-zero row -> max 0
        int idx = h * 64;              // first k of this half
        for (int kk = 0; kk < 64; ++kk) {
            int k = h * 64 + kk;
            float I, D; iou_parts(a, ba, sg[k], sga[k], I, D);
            float cbf = __uint_as_float(colb[k]);  // racy, monotone
            float m = fminf(vb, cbf);
            float mD = m * D;
            // fires iff round(I/D) could beat row OR col record
            // (1-ulp-margined; misses impossible by monotone rounding)
            if (ins & (I > 0.0f) & (I > mD - 1e-6f * mD)) {
                float v = I / D;                   // exact IEEE, THE value
                if (v > vb) { vb = v; idx = k; }   // strict > = first max
                if (v > cbf) atomicMax(&colb[k], __float_as_uint(v));
            }
        }
        abV[h][lo]  = vb;
        aidx[h][lo] = (unsigned char)idx;
    }
    __syncthreads();
    if (t < 128) {
        float v0 = abV[0][t], v1 = abV[1][t];
        bool outs = sba[t] < 0.0f;
        bool c = v1 > v0;                          // strict: half 0 wins ties
        maxov[base + t] = outs ? -1.0f : (c ? v1 : v0);
        argm[base + t]  = (unsigned char)(outs ? 0 : (c ? aidx[1][t] : aidx[0][t]));
    }
    if (t < NK) {
        unsigned e = encf(__uint_as_float(colb[t]));
        if (e > gtm[t]) atomicMax(&gtm[t], e);     // racy prefilter; atomic wins
    }
}

// Labels + bbox targets: in-block gt sort (defer prune), thresholds from maxov,
// inline gt-best for deferred anchors, value-binned hist+bucket, out1 targets.
__global__ __launch_bounds__(256) void k_labels(
    const float4* __restrict__ anchors, const float4* __restrict__ gt,
    const unsigned* __restrict__ gtm,
    const float* __restrict__ maxov, const unsigned char* __restrict__ argm,
    const float* __restrict__ noise,
    float* __restrict__ labels,
    unsigned* __restrict__ hfv, unsigned* __restrict__ hbv,
    float* __restrict__ bfv, float* __restrict__ bbv,
    float4* __restrict__ out1) {
    __shared__ float4 sg[NK];            // sorted gt (defer loop)
    __shared__ float  sga[NK];
    __shared__ float  sgm[NK];
    __shared__ float4 sgo[NK];           // original-order gt (targets)
    __shared__ unsigned se[NK];
    int t = threadIdx.x;
    if (t < NK) se[t] = gtm[t];
    __syncthreads();
    if (t < NK) {
        unsigned e = se[t];
        int rank = 0;
        for (int j = 0; j < NK; ++j) {
            unsigned ej = se[j];
            rank += (ej < e) || (ej == e && j < t);
        }
        float4 g = gt[t];
        sgo[t]    = g;
        sg[rank]  = g;
        sga[rank] = (g.z - g.x + 1.0f) * (g.w - g.y + 1.0f);
        sgm[rank] = (e == 0u) ? 0.0f : decf(e);    // never-updated col: max is 0
    }
    __syncthreads();
    int i = blockIdx.x * 256 + t;
    float mo = maxov[i];
    bool ins = mo >= 0.0f;
    float smin = sgm[0];
    float lab = -1.0f;
    if (ins && mo < 0.3f)  lab = 0.0f;
    if (ins && mo >= 0.7f) lab = 1.0f;
    float4 a = anchors[i];
    bool defer = ins && (mo >= smin) && (mo < 0.7f);
    if (defer) {                               // rare -> divergence cost small
        float ba = (a.z - a.x + 1.0f) * (a.w - a.y + 1.0f);
        bool gb = false;
        for (int q = 0; q < NK; ++q) {
            float gm = sgm[q];
            if (gm > mo) break;                // sorted: no later column can match
            float I, D; iou_parts(a, ba, sg[q], sga[q], I, D);
            float v = I / D;                   // bit-identical to k_rowcol rounding
            gb = gb || (v == gm);
        }
        if (gb) lab = 1.0f;
    }
    labels[i] = lab;
    float nz = noise[i];
    if (lab == 1.0f) {
        unsigned b = vbin(nz);
        unsigned s = atomicAdd(&hfv[b], 1u);
        if (s < BCAP) bfv[b * BCAP + s] = nz;
    } else if (lab == 0.0f) {
        unsigned b = vbin(nz);
        unsigned s = atomicAdd(&hbv[b], 1u);
        if (s < BCAP) bbv[b * BCAP + s] = nz;
    }
    // ---- bbox regression targets (selection-independent) ----
    {
        float4 g = sgo[argm[i]];
        float ew = a.z - a.x + 1.0f, eh = a.w - a.y + 1.0f;
        float ecx = a.x + 0.5f * ew,  ecy = a.y + 0.5f * eh;
        float gw = g.z - g.x + 1.0f,  gh = g.w - g.y + 1.0f;
        float gcx = g.x + 0.5f * gw,  gcy = g.y + 0.5f * gh;
        float t0 = (gcx - ecx) / ew;
        float t1 = (gcy - ecy) / eh;
        float t2 = logf(gw / ew);
        float t3 = logf(gh / eh);
        if (!ins) { t0 = 0.0f; t1 = 0.0f; t2 = 0.0f; t3 = 0.0f; }   // outside
        out1[i] = make_float4(t0, t1, t2, t3);
    }
}

// Selection body: linear 8192-bin scan -> bin+rem -> exact rank among <=64 values.
__device__ __forceinline__ void sel_body(
    const unsigned* __restrict__ hist, const float* __restrict__ bucket,
    unsigned* __restrict__ sc, int isBg,
    int* csum, int* suf, int* sscal, float* sv) {
    int t = threadIdx.x;
    const unsigned* hp = hist + t * 32;
    int s = 0;
    for (int b = 0; b < 32; ++b) s += (int)hp[b];
    csum[t] = s;
    if (t == 0) { sscal[0] = 0; sscal[1] = 1; }
    __syncthreads();
    if (t == 0) {
        int run = 0;
        for (int c = 255; c >= 0; --c) { suf[c] = run; run += csum[c]; }
        sscal[2] = run;
    }
    __syncthreads();
    int total = sscal[2];
    int k, active;
    if (isBg) {
        int nfg = (int)sc[S_NFG_FINAL];
        int nb = 256 - nfg;
        active = total > nb;
        k = nb < 1 ? 1 : nb;
    } else {
        active = total > 128;
        k = 128;
    }
    if (!active) {
        if (t == 0) {
            if (isBg) { sc[S_BG_ACTIVE] = 0u; sc[S_NUM_EX] = sc[S_NFG_FINAL] + (unsigned)total; }
            else      { sc[S_FG_ACTIVE] = 0u; sc[S_NFG_FINAL] = (unsigned)total; }
        }
    } else {
        int above = suf[t];
        if (above < k && k <= above + csum[t]) {
            int c = above;
            for (int b = 31; b >= 0; --b) {
                int hh = (int)hp[b];
                c += hh;
                if (c >= k) { sscal[0] = t * 32 + b; sscal[1] = k - (c - hh); break; }
            }
        }
    }
    __syncthreads();
    if (active) {                                  // block-uniform condition
        int bstar = sscal[0], rem = sscal[1];
        int cnt = (int)hist[bstar];
        if (cnt > BCAP) cnt = BCAP;
        if (t < BCAP) sv[t] = (t < cnt) ? bucket[bstar * BCAP + t] : -INFINITY;
        __syncthreads();
        if (t < cnt) {
            float v = sv[t];
            int a = 0, b2 = 0;
            for (int q = 0; q < cnt; ++q) { float u = sv[q]; a += (u > v); b2 += (u == v); }
            if (a < rem && rem <= a + b2) {        // v is the k-th largest (tie-exact)
                unsigned nk = (unsigned)(k - rem + a + b2);   // count(score >= th)
                if (isBg) { sc[S_BG_TH] = __float_as_uint(v); sc[S_BG_ACTIVE] = 1u;
                            sc[S_NUM_EX] = sc[S_NFG_FINAL] + nk; }
                else      { sc[S_FG_TH] = __float_as_uint(v); sc[S_FG_ACTIVE] = 1u;
                            sc[S_NFG_FINAL] = nk; }
            }
        }
    }
    __syncthreads();                               // publish sc before next pass
}

__global__ __launch_bounds__(256) void k_select(
    const unsigned* __restrict__ hfv, const float* __restrict__ bfv,
    const unsigned* __restrict__ hbv, const float* __restrict__ bbv,
    unsigned* __restrict__ sc) {
    __shared__ int csum[256];
    __shared__ int suf[256];
    __shared__ int sscal[3];
    __shared__ float sv[BCAP];
    sel_body(hfv, bfv, sc, 0, csum, suf, sscal, sv);
    sel_body(hbv, bbv, sc, 1, csum, suf, sscal, sv);
}

// Final: pure streaming. Apply disables; scatter permuted label; weights.
__global__ __launch_bounds__(256) void k_final(
    const float* __restrict__ noise, const float* __restrict__ labels,
    const unsigned* __restrict__ sc,
    float* __restrict__ out0, float4* __restrict__ out2, float4* __restrict__ out3) {
    int i = blockIdx.x * 256 + threadIdx.x;
    unsigned fga = sc[S_FG_ACTIVE], bga = sc[S_BG_ACTIVE];
    float thf = __uint_as_float(sc[S_FG_TH]);
    float thb = __uint_as_float(sc[S_BG_TH]);

    float lab = labels[i];
    float nz = noise[i];
    if (fga && lab == 1.0f && nz < thf) lab = -1.0f;
    if (bga && lab == 0.0f && nz < thb) lab = -1.0f;

    // permuted label: src i = cell*NA + a0 -> dest a0*HW + cell (scatter write)
    int cell = i / NA, a0 = i - cell * NA;
    out0[a0 * HW_ + cell] = lab;

    float biw = (lab == 1.0f) ? 1.0f : 0.0f;
    out2[i] = make_float4(biw, biw, biw, biw);

    float inv = 1.0f / (float)sc[S_NUM_EX];
    float bow = (lab >= 0.0f) ? inv : 0.0f;
    out3[i] = make_float4(bow, bow, bow, bow);
}

extern "C" void kernel_launch(void* const* d_in, const int* in_sizes, int n_in,
                              void* d_out, int out_size, void* d_ws, size_t ws_size,
                              hipStream_t stream) {
    const float4* anchors = (const float4*)d_in[0];
    const float4* gt      = (const float4*)d_in[1];
    const float*  iminfo  = (const float*)d_in[2];
    const float*  noise   = (const float*)d_in[3];

    float*  out0 = (float*)d_out;                  // NN
    float4* out1 = (float4*)(out0 + NN);           // NN x 4 (written by k_labels)
    float4* out2 = (float4*)(out0 + NN + 4 * NN);  // NN x 4
    float4* out3 = (float4*)(out0 + NN + 8 * NN);  // NN x 4

    // value buckets borrow the out2/out3 regions (524288 floats each fits in
    // 921600): written by k_labels, read by k_select, then k_final overwrites.
    float* bfv = (float*)out2;
    float* bbv = (float*)out3;

    char* ws = (char*)d_ws;
    unsigned* sc   = (unsigned*)ws;                         // 128 u32
    unsigned* gtm  = (unsigned*)(ws + 512);                 // 128 u32
    unsigned* hfv  = (unsigned*)(ws + 4096);                // 8192 u32
    unsigned* hbv  = hfv + BINS;                            // 8192 u32 -> ends 69632
    float* labels  = (float*)(ws + 69632);                  // NN f32
    float* maxov   = labels + NN;                           // NN f32
    unsigned char* argm = (unsigned char*)(maxov + NN);     // NN u8

    hipMemsetAsync(ws, 0, 69632, stream);          // sc+gtm+hists (DMA node)
    k_rowcol<<<1800, 256, 0, stream>>>(anchors, gt, iminfo, maxov, argm, gtm);
    k_labels<<<NBLK, 256, 0, stream>>>(anchors, gt, gtm, maxov, argm, noise,
                                       labels, hfv, hbv, bfv, bbv, out1);
    k_select<<<1, 256, 0, stream>>>(hfv, bfv, hbv, bbv, sc);
    k_final<<<NBLK, 256, 0, stream>>>(noise, labels, sc, out0, out2, out3);
}

// Round 15
// 68.634 us; speedup vs baseline: 1.6157x; 1.0250x over previous
//
#include <hip/hip_runtime.h>
#include <hip/hip_bf16.h>

#pragma clang fp contract(off)

#define NN   230400   // H*W*A
#define NK   128      // gt boxes
#define HW_  25600    // H*W
#define NA   9
#define NBLK 900      // NN/256
#define BINS 8192
#define BCAP 64

// ---- scalar slots in ws ----
enum { S_FG_ACTIVE=0, S_FG_TH, S_NFG_FINAL, S_BG_ACTIVE, S_BG_TH, S_NUM_EX };

__device__ __forceinline__ unsigned encf(float f) {
    unsigned u = __float_as_uint(f);
    return (u & 0x80000000u) ? ~u : (u | 0x80000000u);
}
__device__ __forceinline__ float decf(unsigned e) {
    unsigned u = (e & 0x80000000u) ? (e & 0x7FFFFFFFu) : ~e;
    return __uint_as_float(u);
}
// The ONE IoU expression (identical rounding at every use site; contract off).
__device__ __forceinline__ void iou_parts(float4 a, float ba, float4 g, float ga,
                                          float& I, float& D) {
    float iw = fmaxf(fminf(a.z, g.z) - fmaxf(a.x, g.x) + 1.0f, 0.0f);
    float ih = fmaxf(fminf(a.w, g.w) - fmaxf(a.y, g.y) + 1.0f, 0.0f);
    I = iw * ih;
    D = ba + ga - I;          // (ba+ga)-I, same assoc everywhere
}
__device__ __forceinline__ unsigned vbin(float nz) {
    unsigned b = (unsigned)(nz * 8192.0f);
    return b > 8191u ? 8191u : b;
}

// Row+col in ONE visit per pair (R12-validated gate), ALL anchors.
// Outside anchors carry SENTINEL boxes (empty -> I always 0 -> gate never
// fires) so the hot gate needs no inside/I>0 terms: fire iff I > m*D*C1,
// C1 = 1-1e-6 (misses impossible by monotone rounding; false fires = 1 div).
__global__ __launch_bounds__(256) void k_rowcol(
    const float4* __restrict__ anchors, const float4* __restrict__ gt,
    const float* __restrict__ iminfo, float* __restrict__ maxov,
    unsigned char* __restrict__ argm, unsigned* __restrict__ gtm) {
    __shared__ float4 sg[NK];
    __shared__ float  sga[NK];
    __shared__ float4 sa[128];
    __shared__ float  sba[128];        // real ba, or -1 if outside (epilogue flag)
    __shared__ unsigned colb[NK];      // per-column running max (value bits)
    __shared__ float  abV[2][128];
    __shared__ unsigned char aidx[2][128];
    const float C1 = 1.0f - 1e-6f;
    int t = threadIdx.x;
    if (t < NK) {
        float4 g = gt[t];
        sg[t] = g;
        sga[t] = (g.z - g.x + 1.0f) * (g.w - g.y + 1.0f);
        unsigned e0 = gtm[t];          // racy monotone lower bound
        colb[t] = (e0 == 0u) ? 0u : __float_as_uint(decf(e0));
    }
    int base = blockIdx.x * 128;
    if (t < 128) {
        float4 a = anchors[base + t];
        float imh = iminfo[0], imw = iminfo[1];
        bool ins = (a.x >= 0.0f) && (a.y >= 0.0f) && (a.z < imw) && (a.w < imh);
        // sentinel empty box for outside anchors: every iw/ih clamps to 0
        sa[t] = ins ? a : make_float4(3e9f, 3e9f, -3e9f, -3e9f);
        float4 ae = ins ? a : make_float4(3e9f, 3e9f, -3e9f, -3e9f);
        float ba = (ae.z - ae.x + 1.0f) * (ae.w - ae.y + 1.0f);
        sba[t] = ins ? ba : -1.0f;
    }
    __syncthreads();
    int lo = t & 127, h = t >> 7;      // h uniform per wave
    {
        float4 a = sa[lo];
        float ba = (a.z - a.x + 1.0f) * (a.w - a.y + 1.0f);
        float vb = 0.0f;               // inside all-zero row -> max 0
        int idx = h * 64;              // first k of this half
        for (int kk = 0; kk < 64; ++kk) {
            int k = h * 64 + kk;
            float I, D; iou_parts(a, ba, sg[k], sga[k], I, D);
            float cbf = __uint_as_float(colb[k]);  // racy, monotone
            float m = fminf(vb, cbf);
            // fires iff round(I/D) could beat row OR col record
            if (I > m * D * C1) {
                float v = I / D;                   // exact IEEE, THE value
                if (v > vb) { vb = v; idx = k; }   // strict > = first max
                if (v > cbf) atomicMax(&colb[k], __float_as_uint(v));
            }
        }
        abV[h][lo]  = vb;
        aidx[h][lo] = (unsigned char)idx;
    }
    __syncthreads();
    if (t < 128) {
        float v0 = abV[0][t], v1 = abV[1][t];
        bool outs = sba[t] < 0.0f;
        bool c = v1 > v0;                          // strict: half 0 wins ties
        maxov[base + t] = outs ? -1.0f : (c ? v1 : v0);
        argm[base + t]  = (unsigned char)(outs ? 0 : (c ? aidx[1][t] : aidx[0][t]));
    }
    if (t < NK) {
        unsigned e = encf(__uint_as_float(colb[t]));
        if (e > gtm[t]) atomicMax(&gtm[t], e);     // racy prefilter; atomic wins
    }
}

// Labels + bbox targets: in-block gt sort (defer prune), thresholds from maxov,
// inline gt-best for deferred anchors, value-binned hist+bucket, out1 targets.
__global__ __launch_bounds__(256) void k_labels(
    const float4* __restrict__ anchors, const float4* __restrict__ gt,
    const unsigned* __restrict__ gtm,
    const float* __restrict__ maxov, const unsigned char* __restrict__ argm,
    const float* __restrict__ noise,
    float* __restrict__ labels,
    unsigned* __restrict__ hfv, unsigned* __restrict__ hbv,
    float* __restrict__ bfv, float* __restrict__ bbv,
    float4* __restrict__ out1) {
    __shared__ float4 sg[NK];            // sorted gt (defer loop)
    __shared__ float  sga[NK];
    __shared__ float  sgm[NK];
    __shared__ float4 sgo[NK];           // original-order gt (targets)
    __shared__ unsigned se[NK];
    int t = threadIdx.x;
    if (t < NK) se[t] = gtm[t];
    __syncthreads();
    if (t < NK) {
        unsigned e = se[t];
        int rank = 0;
        for (int j = 0; j < NK; ++j) {
            unsigned ej = se[j];
            rank += (ej < e) || (ej == e && j < t);
        }
        float4 g = gt[t];
        sgo[t]    = g;
        sg[rank]  = g;
        sga[rank] = (g.z - g.x + 1.0f) * (g.w - g.y + 1.0f);
        sgm[rank] = (e == 0u) ? 0.0f : decf(e);    // never-updated col: max is 0
    }
    __syncthreads();
    int i = blockIdx.x * 256 + t;
    float mo = maxov[i];
    bool ins = mo >= 0.0f;
    float smin = sgm[0];
    float lab = -1.0f;
    if (ins && mo < 0.3f)  lab = 0.0f;
    if (ins && mo >= 0.7f) lab = 1.0f;
    float4 a = anchors[i];
    bool defer = ins && (mo >= smin) && (mo < 0.7f);
    if (defer) {                               // rare -> divergence cost small
        float ba = (a.z - a.x + 1.0f) * (a.w - a.y + 1.0f);
        bool gb = false;
        for (int q = 0; q < NK; ++q) {
            float gm = sgm[q];
            if (gm > mo) break;                // sorted: no later column can match
            float I, D; iou_parts(a, ba, sg[q], sga[q], I, D);
            float v = I / D;                   // bit-identical to k_rowcol rounding
            gb = gb || (v == gm);
        }
        if (gb) lab = 1.0f;
    }
    labels[i] = lab;
    float nz = noise[i];
    if (lab == 1.0f) {
        unsigned b = vbin(nz);
        unsigned s = atomicAdd(&hfv[b], 1u);
        if (s < BCAP) bfv[b * BCAP + s] = nz;
    } else if (lab == 0.0f) {
        unsigned b = vbin(nz);
        unsigned s = atomicAdd(&hbv[b], 1u);
        if (s < BCAP) bbv[b * BCAP + s] = nz;
    }
    // ---- bbox regression targets (selection-independent) ----
    {
        float4 g = sgo[argm[i]];
        float ew = a.z - a.x + 1.0f, eh = a.w - a.y + 1.0f;
        float ecx = a.x + 0.5f * ew,  ecy = a.y + 0.5f * eh;
        float gw = g.z - g.x + 1.0f,  gh = g.w - g.y + 1.0f;
        float gcx = g.x + 0.5f * gw,  gcy = g.y + 0.5f * gh;
        float t0 = (gcx - ecx) / ew;
        float t1 = (gcy - ecy) / eh;
        float t2 = logf(gw / ew);
        float t3 = logf(gh / eh);
        if (!ins) { t0 = 0.0f; t1 = 0.0f; t2 = 0.0f; t3 = 0.0f; }   // outside
        out1[i] = make_float4(t0, t1, t2, t3);
    }
}

// Selection body: linear 8192-bin scan -> bin+rem -> exact rank among <=64 values.
__device__ __forceinline__ void sel_body(
    const unsigned* __restrict__ hist, const float* __restrict__ bucket,
    unsigned* __restrict__ sc, int isBg,
    int* csum, int* suf, int* sscal, float* sv) {
    int t = threadIdx.x;
    const unsigned* hp = hist + t * 32;
    int s = 0;
    for (int b = 0; b < 32; ++b) s += (int)hp[b];
    csum[t] = s;
    if (t == 0) { sscal[0] = 0; sscal[1] = 1; }
    __syncthreads();
    if (t == 0) {
        int run = 0;
        for (int c = 255; c >= 0; --c) { suf[c] = run; run += csum[c]; }
        sscal[2] = run;
    }
    __syncthreads();
    int total = sscal[2];
    int k, active;
    if (isBg) {
        int nfg = (int)sc[S_NFG_FINAL];
        int nb = 256 - nfg;
        active = total > nb;
        k = nb < 1 ? 1 : nb;
    } else {
        active = total > 128;
        k = 128;
    }
    if (!active) {
        if (t == 0) {
            if (isBg) { sc[S_BG_ACTIVE] = 0u; sc[S_NUM_EX] = sc[S_NFG_FINAL] + (unsigned)total; }
            else      { sc[S_FG_ACTIVE] = 0u; sc[S_NFG_FINAL] = (unsigned)total; }
        }
    } else {
        int above = suf[t];
        if (above < k && k <= above + csum[t]) {
            int c = above;
            for (int b = 31; b >= 0; --b) {
                int hh = (int)hp[b];
                c += hh;
                if (c >= k) { sscal[0] = t * 32 + b; sscal[1] = k - (c - hh); break; }
            }
        }
    }
    __syncthreads();
    if (active) {                                  // block-uniform condition
        int bstar = sscal[0], rem = sscal[1];
        int cnt = (int)hist[bstar];
        if (cnt > BCAP) cnt = BCAP;
        if (t < BCAP) sv[t] = (t < cnt) ? bucket[bstar * BCAP + t] : -INFINITY;
        __syncthreads();
        if (t < cnt) {
            float v = sv[t];
            int a = 0, b2 = 0;
            for (int q = 0; q < cnt; ++q) { float u = sv[q]; a += (u > v); b2 += (u == v); }
            if (a < rem && rem <= a + b2) {        // v is the k-th largest (tie-exact)
                unsigned nk = (unsigned)(k - rem + a + b2);   // count(score >= th)
                if (isBg) { sc[S_BG_TH] = __float_as_uint(v); sc[S_BG_ACTIVE] = 1u;
                            sc[S_NUM_EX] = sc[S_NFG_FINAL] + nk; }
                else      { sc[S_FG_TH] = __float_as_uint(v); sc[S_FG_ACTIVE] = 1u;
                            sc[S_NFG_FINAL] = nk; }
            }
        }
    }
    __syncthreads();                               // publish sc before next pass
}

__global__ __launch_bounds__(256) void k_select(
    const unsigned* __restrict__ hfv, const float* __restrict__ bfv,
    const unsigned* __restrict__ hbv, const float* __restrict__ bbv,
    unsigned* __restrict__ sc) {
    __shared__ int csum[256];
    __shared__ int suf[256];
    __shared__ int sscal[3];
    __shared__ float sv[BCAP];
    sel_body(hfv, bfv, sc, 0, csum, suf, sscal, sv);
    sel_body(hbv, bbv, sc, 1, csum, suf, sscal, sv);
}

// Final: pure streaming. Apply disables; scatter permuted label; weights.
__global__ __launch_bounds__(256) void k_final(
    const float* __restrict__ noise, const float* __restrict__ labels,
    const unsigned* __restrict__ sc,
    float* __restrict__ out0, float4* __restrict__ out2, float4* __restrict__ out3) {
    int i = blockIdx.x * 256 + threadIdx.x;
    unsigned fga = sc[S_FG_ACTIVE], bga = sc[S_BG_ACTIVE];
    float thf = __uint_as_float(sc[S_FG_TH]);
    float thb = __uint_as_float(sc[S_BG_TH]);

    float lab = labels[i];
    float nz = noise[i];
    if (fga && lab == 1.0f && nz < thf) lab = -1.0f;
    if (bga && lab == 0.0f && nz < thb) lab = -1.0f;

    // permuted label: src i = cell*NA + a0 -> dest a0*HW + cell (scatter write)
    int cell = i / NA, a0 = i - cell * NA;
    out0[a0 * HW_ + cell] = lab;

    float biw = (lab == 1.0f) ? 1.0f : 0.0f;
    out2[i] = make_float4(biw, biw, biw, biw);

    float inv = 1.0f / (float)sc[S_NUM_EX];
    float bow = (lab >= 0.0f) ? inv : 0.0f;
    out3[i] = make_float4(bow, bow, bow, bow);
}

extern "C" void kernel_launch(void* const* d_in, const int* in_sizes, int n_in,
                              void* d_out, int out_size, void* d_ws, size_t ws_size,
                              hipStream_t stream) {
    const float4* anchors = (const float4*)d_in[0];
    const float4* gt      = (const float4*)d_in[1];
    const float*  iminfo  = (const float*)d_in[2];
    const float*  noise   = (const float*)d_in[3];

    float*  out0 = (float*)d_out;                  // NN
    float4* out1 = (float4*)(out0 + NN);           // NN x 4 (written by k_labels)
    float4* out2 = (float4*)(out0 + NN + 4 * NN);  // NN x 4
    float4* out3 = (float4*)(out0 + NN + 8 * NN);  // NN x 4

    // value buckets borrow the out2/out3 regions (524288 floats each fits in
    // 921600): written by k_labels, read by k_select, then k_final overwrites.
    float* bfv = (float*)out2;
    float* bbv = (float*)out3;

    char* ws = (char*)d_ws;
    unsigned* sc   = (unsigned*)ws;                         // 128 u32
    unsigned* gtm  = (unsigned*)(ws + 512);                 // 128 u32
    unsigned* hfv  = (unsigned*)(ws + 4096);                // 8192 u32
    unsigned* hbv  = hfv + BINS;                            // 8192 u32 -> ends 69632
    float* labels  = (float*)(ws + 69632);                  // NN f32
    float* maxov   = labels + NN;                           // NN f32
    unsigned char* argm = (unsigned char*)(maxov + NN);     // NN u8

    hipMemsetAsync(ws, 0, 69632, stream);          // sc+gtm+hists (DMA node)
    k_rowcol<<<1800, 256, 0, stream>>>(anchors, gt, iminfo, maxov, argm, gtm);
    k_labels<<<NBLK, 256, 0, stream>>>(anchors, gt, gtm, maxov, argm, noise,
                                       labels, hfv, hbv, bfv, bbv, out1);
    k_select<<<1, 256, 0, stream>>>(hfv, bfv, hbv, bbv, sc);
    k_final<<<NBLK, 256, 0, stream>>>(noise, labels, sc, out0, out2, out3);
}

// Round 16
// 68.562 us; speedup vs baseline: 1.6174x; 1.0010x over previous
//
#include <hip/hip_runtime.h>
#include <hip/hip_bf16.h>

#pragma clang fp contract(off)

#define NN   230400   // H*W*A
#define NK   128      // gt boxes
#define HW_  25600    // H*W
#define NA   9
#define NBLK 900      // NN/256
#define BINS 8192
#define BCAP 64

// ---- scalar slots in ws ----
enum { S_FG_ACTIVE=0, S_FG_TH, S_NFG_FINAL, S_BG_ACTIVE, S_BG_TH, S_NUM_EX };

__device__ __forceinline__ unsigned encf(float f) {
    unsigned u = __float_as_uint(f);
    return (u & 0x80000000u) ? ~u : (u | 0x80000000u);
}
__device__ __forceinline__ float decf(unsigned e) {
    unsigned u = (e & 0x80000000u) ? (e & 0x7FFFFFFFu) : ~e;
    return __uint_as_float(u);
}
// The ONE IoU expression (identical rounding at every use site; contract off).
__device__ __forceinline__ void iou_parts(float4 a, float ba, float4 g, float ga,
                                          float& I, float& D) {
    float iw = fmaxf(fminf(a.z, g.z) - fmaxf(a.x, g.x) + 1.0f, 0.0f);
    float ih = fmaxf(fminf(a.w, g.w) - fmaxf(a.y, g.y) + 1.0f, 0.0f);
    I = iw * ih;
    D = ba + ga - I;          // (ba+ga)-I, same assoc everywhere
}
__device__ __forceinline__ unsigned vbin(float nz) {
    unsigned b = (unsigned)(nz * 8192.0f);
    return b > 8191u ? 8191u : b;
}

// Row+col in ONE visit per pair. Hot gate uses REGISTER-ONLY bound
// m = min(vb, hm) where hm = min of the half's seeded column bounds
// (stale-safe: bounds only grow). colb is read from LDS only on fire
// (~10% of iters). Misses impossible: v > colb[k] >= seed >= hm => fires;
// v > vb >= m => fires; C1 margin covers product roundings.
__global__ __launch_bounds__(256) void k_rowcol(
    const float4* __restrict__ anchors, const float4* __restrict__ gt,
    const float* __restrict__ iminfo, float* __restrict__ maxov,
    unsigned char* __restrict__ argm, unsigned* __restrict__ gtm) {
    __shared__ float4 sg[NK];
    __shared__ float  sga[NK];
    __shared__ float4 sa[128];
    __shared__ float  sba[128];        // real ba, or -1 if outside (epilogue flag)
    __shared__ unsigned colb[NK];      // per-column running max (value bits)
    __shared__ float  hminS[2];        // per-half min of seeded colb
    __shared__ float  abV[2][128];
    __shared__ unsigned char aidx[2][128];
    const float C1 = 1.0f - 1e-6f;
    int t = threadIdx.x;
    if (t < NK) {
        float4 g = gt[t];
        sg[t] = g;
        sga[t] = (g.z - g.x + 1.0f) * (g.w - g.y + 1.0f);
        unsigned e0 = gtm[t];          // racy monotone lower bound
        colb[t] = (e0 == 0u) ? 0u : __float_as_uint(decf(e0));
    }
    int base = blockIdx.x * 128;
    if (t < 128) {
        float4 a = anchors[base + t];
        float imh = iminfo[0], imw = iminfo[1];
        bool ins = (a.x >= 0.0f) && (a.y >= 0.0f) && (a.z < imw) && (a.w < imh);
        // sentinel empty box for outside anchors: every iw/ih clamps to 0
        sa[t] = ins ? a : make_float4(3e9f, 3e9f, -3e9f, -3e9f);
        sba[t] = ins ? (a.z - a.x + 1.0f) * (a.w - a.y + 1.0f) : -1.0f;
    }
    __syncthreads();
    if (t < 2) {                       // per-half static lower bound
        float mn = __uint_as_float(colb[t * 64]);
        for (int q = 1; q < 64; ++q) mn = fminf(mn, __uint_as_float(colb[t * 64 + q]));
        hminS[t] = mn;
    }
    __syncthreads();
    int lo = t & 127, h = t >> 7;      // h uniform per wave
    {
        float4 a = sa[lo];
        float ba = (a.z - a.x + 1.0f) * (a.w - a.y + 1.0f);
        float hm = hminS[h];
        float vb = 0.0f;               // inside all-zero row -> max 0
        float m = 0.0f;                // fminf(vb=0, hm>=0) == 0
        int idx = h * 64;              // first k of this half
        for (int kk = 0; kk < 64; ++kk) {
            int k = h * 64 + kk;
            float I, D; iou_parts(a, ba, sg[k], sga[k], I, D);
            // fires iff round(I/D) could beat row record OR any col record
            if (I > m * D * C1) {
                float v = I / D;                   // exact IEEE, THE value
                float cbf = __uint_as_float(colb[k]);
                if (v > vb) { vb = v; idx = k; m = fminf(vb, hm); }  // first max
                if (v > cbf) atomicMax(&colb[k], __float_as_uint(v));
            }
        }
        abV[h][lo]  = vb;
        aidx[h][lo] = (unsigned char)idx;
    }
    __syncthreads();
    if (t < 128) {
        float v0 = abV[0][t], v1 = abV[1][t];
        bool outs = sba[t] < 0.0f;
        bool c = v1 > v0;                          // strict: half 0 wins ties
        maxov[base + t] = outs ? -1.0f : (c ? v1 : v0);
        argm[base + t]  = (unsigned char)(outs ? 0 : (c ? aidx[1][t] : aidx[0][t]));
    }
    if (t < NK) {
        unsigned e = encf(__uint_as_float(colb[t]));
        if (e > gtm[t]) atomicMax(&gtm[t], e);     // racy prefilter; atomic wins
    }
}

// Labels + bbox targets: in-block gt sort (defer prune), thresholds from maxov,
// inline gt-best for deferred anchors, value-binned hist+bucket, out1 targets.
__global__ __launch_bounds__(256) void k_labels(
    const float4* __restrict__ anchors, const float4* __restrict__ gt,
    const unsigned* __restrict__ gtm,
    const float* __restrict__ maxov, const unsigned char* __restrict__ argm,
    const float* __restrict__ noise,
    float* __restrict__ labels,
    unsigned* __restrict__ hfv, unsigned* __restrict__ hbv,
    float* __restrict__ bfv, float* __restrict__ bbv,
    float4* __restrict__ out1) {
    __shared__ float4 sg[NK];            // sorted gt (defer loop)
    __shared__ float  sga[NK];
    __shared__ float  sgm[NK];
    __shared__ float4 sgo[NK];           // original-order gt (targets)
    __shared__ unsigned se[NK];
    int t = threadIdx.x;
    if (t < NK) se[t] = gtm[t];
    __syncthreads();
    if (t < NK) {
        unsigned e = se[t];
        int rank = 0;
        for (int j = 0; j < NK; ++j) {
            unsigned ej = se[j];
            rank += (ej < e) || (ej == e && j < t);
        }
        float4 g = gt[t];
        sgo[t]    = g;
        sg[rank]  = g;
        sga[rank] = (g.z - g.x + 1.0f) * (g.w - g.y + 1.0f);
        sgm[rank] = (e == 0u) ? 0.0f : decf(e);    // never-updated col: max is 0
    }
    __syncthreads();
    int i = blockIdx.x * 256 + t;
    float mo = maxov[i];
    bool ins = mo >= 0.0f;
    float smin = sgm[0];
    float lab = -1.0f;
    if (ins && mo < 0.3f)  lab = 0.0f;
    if (ins && mo >= 0.7f) lab = 1.0f;
    float4 a = anchors[i];
    bool defer = ins && (mo >= smin) && (mo < 0.7f);
    if (defer) {                               // rare -> divergence cost small
        float ba = (a.z - a.x + 1.0f) * (a.w - a.y + 1.0f);
        bool gb = false;
        for (int q = 0; q < NK; ++q) {
            float gm = sgm[q];
            if (gm > mo) break;                // sorted: no later column can match
            float I, D; iou_parts(a, ba, sg[q], sga[q], I, D);
            float v = I / D;                   // bit-identical to k_rowcol rounding
            gb = gb || (v == gm);
        }
        if (gb) lab = 1.0f;
    }
    labels[i] = lab;
    float nz = noise[i];
    if (lab == 1.0f) {
        unsigned b = vbin(nz);
        unsigned s = atomicAdd(&hfv[b], 1u);
        if (s < BCAP) bfv[b * BCAP + s] = nz;
    } else if (lab == 0.0f) {
        unsigned b = vbin(nz);
        unsigned s = atomicAdd(&hbv[b], 1u);
        if (s < BCAP) bbv[b * BCAP + s] = nz;
    }
    // ---- bbox regression targets (selection-independent) ----
    {
        float4 g = sgo[argm[i]];
        float ew = a.z - a.x + 1.0f, eh = a.w - a.y + 1.0f;
        float ecx = a.x + 0.5f * ew,  ecy = a.y + 0.5f * eh;
        float gw = g.z - g.x + 1.0f,  gh = g.w - g.y + 1.0f;
        float gcx = g.x + 0.5f * gw,  gcy = g.y + 0.5f * gh;
        float t0 = (gcx - ecx) / ew;
        float t1 = (gcy - ecy) / eh;
        float t2 = logf(gw / ew);
        float t3 = logf(gh / eh);
        if (!ins) { t0 = 0.0f; t1 = 0.0f; t2 = 0.0f; t3 = 0.0f; }   // outside
        out1[i] = make_float4(t0, t1, t2, t3);
    }
}

// Selection body: linear 8192-bin scan -> bin+rem -> exact rank among <=64 values.
__device__ __forceinline__ void sel_body(
    const unsigned* __restrict__ hist, const float* __restrict__ bucket,
    unsigned* __restrict__ sc, int isBg,
    int* csum, int* suf, int* sscal, float* sv) {
    int t = threadIdx.x;
    const unsigned* hp = hist + t * 32;
    int s = 0;
    for (int b = 0; b < 32; ++b) s += (int)hp[b];
    csum[t] = s;
    if (t == 0) { sscal[0] = 0; sscal[1] = 1; }
    __syncthreads();
    if (t == 0) {
        int run = 0;
        for (int c = 255; c >= 0; --c) { suf[c] = run; run += csum[c]; }
        sscal[2] = run;
    }
    __syncthreads();
    int total = sscal[2];
    int k, active;
    if (isBg) {
        int nfg = (int)sc[S_NFG_FINAL];
        int nb = 256 - nfg;
        active = total > nb;
        k = nb < 1 ? 1 : nb;
    } else {
        active = total > 128;
        k = 128;
    }
    if (!active) {
        if (t == 0) {
            if (isBg) { sc[S_BG_ACTIVE] = 0u; sc[S_NUM_EX] = sc[S_NFG_FINAL] + (unsigned)total; }
            else      { sc[S_FG_ACTIVE] = 0u; sc[S_NFG_FINAL] = (unsigned)total; }
        }
    } else {
        int above = suf[t];
        if (above < k && k <= above + csum[t]) {
            int c = above;
            for (int b = 31; b >= 0; --b) {
                int hh = (int)hp[b];
                c += hh;
                if (c >= k) { sscal[0] = t * 32 + b; sscal[1] = k - (c - hh); break; }
            }
        }
    }
    __syncthreads();
    if (active) {                                  // block-uniform condition
        int bstar = sscal[0], rem = sscal[1];
        int cnt = (int)hist[bstar];
        if (cnt > BCAP) cnt = BCAP;
        if (t < BCAP) sv[t] = (t < cnt) ? bucket[bstar * BCAP + t] : -INFINITY;
        __syncthreads();
        if (t < cnt) {
            float v = sv[t];
            int a = 0, b2 = 0;
            for (int q = 0; q < cnt; ++q) { float u = sv[q]; a += (u > v); b2 += (u == v); }
            if (a < rem && rem <= a + b2) {        // v is the k-th largest (tie-exact)
                unsigned nk = (unsigned)(k - rem + a + b2);   // count(score >= th)
                if (isBg) { sc[S_BG_TH] = __float_as_uint(v); sc[S_BG_ACTIVE] = 1u;
                            sc[S_NUM_EX] = sc[S_NFG_FINAL] + nk; }
                else      { sc[S_FG_TH] = __float_as_uint(v); sc[S_FG_ACTIVE] = 1u;
                            sc[S_NFG_FINAL] = nk; }
            }
        }
    }
    __syncthreads();                               // publish sc before next pass
}

__global__ __launch_bounds__(256) void k_select(
    const unsigned* __restrict__ hfv, const float* __restrict__ bfv,
    const unsigned* __restrict__ hbv, const float* __restrict__ bbv,
    unsigned* __restrict__ sc) {
    __shared__ int csum[256];
    __shared__ int suf[256];
    __shared__ int sscal[3];
    __shared__ float sv[BCAP];
    sel_body(hfv, bfv, sc, 0, csum, suf, sscal, sv);
    sel_body(hbv, bbv, sc, 1, csum, suf, sscal, sv);
}

// Final: pure streaming. Apply disables; scatter permuted label; weights.
__global__ __launch_bounds__(256) void k_final(
    const float* __restrict__ noise, const float* __restrict__ labels,
    const unsigned* __restrict__ sc,
    float* __restrict__ out0, float4* __restrict__ out2, float4* __restrict__ out3) {
    int i = blockIdx.x * 256 + threadIdx.x;
    unsigned fga = sc[S_FG_ACTIVE], bga = sc[S_BG_ACTIVE];
    float thf = __uint_as_float(sc[S_FG_TH]);
    float thb = __uint_as_float(sc[S_BG_TH]);

    float lab = labels[i];
    float nz = noise[i];
    if (fga && lab == 1.0f && nz < thf) lab = -1.0f;
    if (bga && lab == 0.0f && nz < thb) lab = -1.0f;

    // permuted label: src i = cell*NA + a0 -> dest a0*HW + cell (scatter write)
    int cell = i / NA, a0 = i - cell * NA;
    out0[a0 * HW_ + cell] = lab;

    float biw = (lab == 1.0f) ? 1.0f : 0.0f;
    out2[i] = make_float4(biw, biw, biw, biw);

    float inv = 1.0f / (float)sc[S_NUM_EX];
    float bow = (lab >= 0.0f) ? inv : 0.0f;
    out3[i] = make_float4(bow, bow, bow, bow);
}

extern "C" void kernel_launch(void* const* d_in, const int* in_sizes, int n_in,
                              void* d_out, int out_size, void* d_ws, size_t ws_size,
                              hipStream_t stream) {
    const float4* anchors = (const float4*)d_in[0];
    const float4* gt      = (const float4*)d_in[1];
    const float*  iminfo  = (const float*)d_in[2];
    const float*  noise   = (const float*)d_in[3];

    float*  out0 = (float*)d_out;                  // NN
    float4* out1 = (float4*)(out0 + NN);           // NN x 4 (written by k_labels)
    float4* out2 = (float4*)(out0 + NN + 4 * NN);  // NN x 4
    float4* out3 = (float4*)(out0 + NN + 8 * NN);  // NN x 4

    // value buckets borrow the out2/out3 regions (524288 floats each fits in
    // 921600): written by k_labels, read by k_select, then k_final overwrites.
    float* bfv = (float*)out2;
    float* bbv = (float*)out3;

    char* ws = (char*)d_ws;
    unsigned* sc   = (unsigned*)ws;                         // 128 u32
    unsigned* gtm  = (unsigned*)(ws + 512);                 // 128 u32
    unsigned* hfv  = (unsigned*)(ws + 4096);                // 8192 u32
    unsigned* hbv  = hfv + BINS;                            // 8192 u32 -> ends 69632
    float* labels  = (float*)(ws + 69632);                  // NN f32
    float* maxov   = labels + NN;                           // NN f32
    unsigned char* argm = (unsigned char*)(maxov + NN);     // NN u8

    hipMemsetAsync(ws, 0, 69632, stream);          // sc+gtm+hists (DMA node)
    k_rowcol<<<1800, 256, 0, stream>>>(anchors, gt, iminfo, maxov, argm, gtm);
    k_labels<<<NBLK, 256, 0, stream>>>(anchors, gt, gtm, maxov, argm, noise,
                                       labels, hfv, hbv, bfv, bbv, out1);
    k_select<<<1, 256, 0, stream>>>(hfv, bfv, hbv, bbv, sc);
    k_final<<<NBLK, 256, 0, stream>>>(noise, labels, sc, out0, out2, out3);
}